// Round 6
// baseline (165.891 us; speedup 1.0000x reference)
//
#include <hip/hip_runtime.h>
#include <stdint.h>

// Problem: B=16, C=64, H=W=128. fp32 in/out.
#define NB   16
#define NCH  64
#define HH   128
#define NPOS (HH*HH)        // 16384 spatial positions

typedef short bf16x8 __attribute__((ext_vector_type(8)));   // 8 bf16 = 4 VGPRs
typedef float f32x4  __attribute__((ext_vector_type(4)));

__device__ __forceinline__ unsigned short f2bf(float f){
  unsigned int u = __float_as_uint(f);
  u += 0x7FFFu + ((u>>16)&1u);          // RNE; inputs finite
  return (unsigned short)(u>>16);
}
__device__ __forceinline__ unsigned int pk2(float a, float b){
  return (unsigned int)f2bf(a) | ((unsigned int)f2bf(b)<<16);
}
__device__ __forceinline__ bf16x8 pk8(float4 a, float4 b){
  union { bf16x8 v; unsigned int u[4]; } r;
  r.u[0] = pk2(a.x, a.y); r.u[1] = pk2(a.z, a.w);
  r.u[2] = pk2(b.x, b.y); r.u[3] = pk2(b.z, b.w);
  return r.v;
}

// XOR swizzle on byte bits 4-6: spreads 16 consecutive rows over 8 16B slots.
__device__ __forceinline__ int swz(int row, int cb){
  return cb ^ (((row & 7) ^ ((row >> 3) & 7)) << 4);
}
__device__ __forceinline__ unsigned short elem16(uint4 v, int u){
  unsigned int d = (&v.x)[u>>1];
  return (unsigned short)((u&1) ? (d>>16) : (d&0xffffu));
}

// ---------------- Kernel 1: Q/V (m=0, from x) and K (m=1, from att) -------
// MFMA conv1x1+ReLU -> bf16. 256 thr, 128-position tile.
// LDS = Xs only (16KB): W/bias fragments loaded directly from global (L2-hot)
// -> 6-8 blocks/CU. Output via LDS bounce (reuses Xs) -> coalesced uint4.
__global__ __launch_bounds__(256, 6) void rc_conv_in(
    const float* __restrict__ x, const float* __restrict__ att,
    const float* __restrict__ w0, const float* __restrict__ b0,
    const float* __restrict__ w1, const float* __restrict__ b1,
    const float* __restrict__ w2, const float* __restrict__ b2,
    unsigned short* __restrict__ Qb, unsigned short* __restrict__ Kb,
    unsigned short* __restrict__ Vb)
{
  __shared__ char Xs[16384];           // 128 p-rows x 128 B; bounce: 64 x 256 B

  const int tid = threadIdx.x;
  const int m  = blockIdx.z;
  const int b  = blockIdx.y;
  const int pblock = blockIdx.x * 128;
  const float* src = m ? att : x;
  const int w = tid>>6, l = tid&63, lq = l>>4, lm = l&15;
  const int orow = 16*w + lm;

  // ---- W fragments direct from global (L2-cached across blocks) ----
  const float* wAp = (m ? w1 : w0) + orow*64;
  bf16x8 aQ[2], aV[2] = {};
  {
    float4 a0 = *(const float4*)(wAp + lq*8);
    float4 a1 = *(const float4*)(wAp + lq*8 + 4);
    float4 a2 = *(const float4*)(wAp + 32 + lq*8);
    float4 a3 = *(const float4*)(wAp + 32 + lq*8 + 4);
    aQ[0] = pk8(a0, a1); aQ[1] = pk8(a2, a3);
    if (m == 0){
      const float* wBp = w2 + orow*64;
      float4 g0 = *(const float4*)(wBp + lq*8);
      float4 g1 = *(const float4*)(wBp + lq*8 + 4);
      float4 g2 = *(const float4*)(wBp + 32 + lq*8);
      float4 g3 = *(const float4*)(wBp + 32 + lq*8 + 4);
      aV[0] = pk8(g0, g1); aV[1] = pk8(g2, g3);
    }
  }
  float4 bQ4 = *(const float4*)((m ? b1 : b0) + 16*w + 4*lq);
  float4 bV4 = (m==0) ? *(const float4*)(b2 + 16*w + 4*lq) : (float4){0,0,0,0};

  // ---- stage X tile: all 8 loads in flight, then transpose-pack to LDS ----
  const float* S = src + (size_t)b*NCH*NPOS + pblock;
  float4 xr[2][4];
  #pragma unroll
  for (int g=0; g<2; ++g){
    int unit = tid + 256*g;           // 0..511 = 16 cquads x 32 pgroups
    int q  = unit >> 5;               // channel quad 0..15
    int p4 = (unit & 31) << 2;        // position 0..127 step 4
    #pragma unroll
    for (int j=0;j<4;j++)
      xr[g][j] = *(const float4*)(S + (size_t)(4*q+j)*NPOS + p4);
  }
  #pragma unroll
  for (int g=0; g<2; ++g){
    int unit = tid + 256*g;
    int q  = unit >> 5;
    int p4 = (unit & 31) << 2;
    const float* c0 = (const float*)&xr[g][0];
    const float* c1 = (const float*)&xr[g][1];
    const float* c2 = (const float*)&xr[g][2];
    const float* c3 = (const float*)&xr[g][3];
    #pragma unroll
    for (int u=0; u<4; ++u){
      uint2 pk;
      pk.x = pk2(c0[u], c1[u]);
      pk.y = pk2(c2[u], c3[u]);
      *(uint2*)(Xs + (p4+u)*128 + swz(p4+u, q*8)) = pk;
    }
  }
  __syncthreads();

  // ---- MFMA: D[o',p'] = sum_c W[o,c]*X[p,c] ----
  f32x4 accQ[8], accV[8];
  #pragma unroll
  for (int pt=0;pt<8;pt++){ accQ[pt]=(f32x4){0,0,0,0}; accV[pt]=(f32x4){0,0,0,0}; }
  #pragma unroll
  for (int pt=0; pt<8; ++pt){
    int prow = pt*16 + lm;
    bf16x8 bx0 = *(const bf16x8*)(Xs + prow*128 + swz(prow,      lq*16));
    bf16x8 bx1 = *(const bf16x8*)(Xs + prow*128 + swz(prow, 64 + lq*16));
    accQ[pt] = __builtin_amdgcn_mfma_f32_16x16x32_bf16(aQ[0], bx0, accQ[pt], 0,0,0);
    accQ[pt] = __builtin_amdgcn_mfma_f32_16x16x32_bf16(aQ[1], bx1, accQ[pt], 0,0,0);
    if (m == 0){
      accV[pt] = __builtin_amdgcn_mfma_f32_16x16x32_bf16(aV[0], bx0, accV[pt], 0,0,0);
      accV[pt] = __builtin_amdgcn_mfma_f32_16x16x32_bf16(aV[1], bx1, accV[pt], 0,0,0);
    }
  }

  // ---- bounce + coalesced store (Xs reused as 64 o-rows x 256 B) ----
  unsigned short* dA = (m ? Kb : Qb) + (size_t)b*NCH*NPOS;
  unsigned short* dB = Vb + (size_t)b*NCH*NPOS;
  const float* bQv = (const float*)&bQ4;
  const float* bVv = (const float*)&bV4;
  const int skw = 32*((4*w + lq) & 7);     // = 32*((o>>2)&7) for this quarter

  __syncthreads();                          // all MFMA frag reads of Xs done
  #pragma unroll
  for (int pt=0; pt<8; ++pt){
    #pragma unroll
    for (int r4=0;r4<4;r4++){
      int o = 16*w + 4*lq + r4;
      int p = pt*16 + lm;
      *(unsigned short*)(Xs + o*256 + ((2*p + skw) & 255)) =
          f2bf(fmaxf(accQ[pt][r4] + bQv[r4], 0.f));
    }
  }
  __syncthreads();
  {
    int o = tid >> 2, jj = tid & 3;
    int sk2 = 32*((o>>2)&7);
    #pragma unroll
    for (int i=0;i<4;i++){
      int j = i*4 + jj;                    // 16B chunk index in row
      uint4 v = *(const uint4*)(Xs + o*256 + ((j*16 + sk2) & 255));
      *(uint4*)(dA + (size_t)o*NPOS + pblock + j*8) = v;
    }
  }
  if (m == 0){
    __syncthreads();                        // store-reads done before overwrite
    #pragma unroll
    for (int pt=0; pt<8; ++pt){
      #pragma unroll
      for (int r4=0;r4<4;r4++){
        int o = 16*w + 4*lq + r4;
        int p = pt*16 + lm;
        *(unsigned short*)(Xs + o*256 + ((2*p + skw) & 255)) =
            f2bf(fmaxf(accV[pt][r4] + bVv[r4], 0.f));
      }
    }
    __syncthreads();
    int o = tid >> 2, jj = tid & 3;
    int sk2 = 32*((o>>2)&7);
    #pragma unroll
    for (int i=0;i<4;i++){
      int j = i*4 + jj;
      uint4 v = *(const uint4*)(Xs + o*256 + ((j*16 + sk2) & 255));
      *(uint4*)(dB + (size_t)o*NPOS + pblock + j*8) = v;
    }
  }
}

// ---------------- Kernel 2: fused per-(b,c) MFMA attention ----------------
// 1024 blocks x 256 threads (4 waves). LDS = 2 x 32KB -> 2 blocks/CU, two
// independent barrier domains overlap each other's stalls.
// X: Q rm -> QT rm -> VT rm -> M rm ; Y: K rm -> KT rm -> A1 rm -> A2T rm.
// Wave w owns a 32-row strip = 2 substrips cs of 16 rows.
__global__ __launch_bounds__(256, 2) void rc_attention_mfma(
    const unsigned short* __restrict__ Qb, const unsigned short* __restrict__ Kb,
    const unsigned short* __restrict__ Vb, unsigned short* __restrict__ Pb)
{
  extern __shared__ char lds[];
  char* X = lds;
  char* Y = lds + 32768;
  const int tid = threadIdx.x;
  const int l  = tid & 63;
  const int w  = tid >> 6;          // wave 0..3
  const int lq = l >> 4;            // quarter 0..3
  const int lm = l & 15;
  const int ws = 32 * w;            // wave strip base
  const size_t gbase = (size_t)blockIdx.x * NPOS;

  // ---- load Q,K (held in regs for rm write AND later transposed write) ----
  uint4 qr[8], kr[8];
  #pragma unroll
  for (int i=0;i<8;i++){
    size_t e = (size_t)(tid + 256*i)*8;
    qr[i] = *(const uint4*)(Qb + gbase + e);
    kr[i] = *(const uint4*)(Kb + gbase + e);
  }
  #pragma unroll
  for (int i=0;i<8;i++){
    int e = (tid + 256*i)*8;
    int row = e >> 7, col = e & 127;
    *(uint4*)(X + row*256 + swz(row, col*2)) = qr[i];
    *(uint4*)(Y + row*256 + swz(row, col*2)) = kr[i];
  }
  __syncthreads();

  // ---- P1: S1T = K·Q^T. D[m=j'][n=r']: j=jt*16+4lq+r4, r=ws+16cs+lm ----
  f32x4 acc1[2][8];
  #pragma unroll
  for (int cs=0;cs<2;cs++)
    #pragma unroll
    for (int t=0;t<8;t++) acc1[cs][t] = (f32x4){0.f,0.f,0.f,0.f};
  {
    bf16x8 bq[2][4];
    #pragma unroll
    for (int cs=0;cs<2;cs++)
      #pragma unroll
      for (int kk=0;kk<4;kk++){
        int r = ws + 16*cs + lm;
        bq[cs][kk] = *(const bf16x8*)(X + r*256 + swz(r, kk*64 + lq*16));
      }
    #pragma unroll
    for (int kk=0;kk<4;kk++){
      #pragma unroll
      for (int jt=0;jt<8;jt++){
        int jr = jt*16 + lm;
        bf16x8 ak = *(const bf16x8*)(Y + jr*256 + swz(jr, kk*64 + lq*16));
        acc1[0][jt] = __builtin_amdgcn_mfma_f32_16x16x32_bf16(ak, bq[0][kk], acc1[0][jt], 0,0,0);
        acc1[1][jt] = __builtin_amdgcn_mfma_f32_16x16x32_bf16(ak, bq[1][kk], acc1[1][jt], 0,0,0);
      }
    }
  }
  // softmax over j (in-lane 32 + shfl_xor 16/32), per substrip cs
  unsigned int a1p[2][8][2];
  #pragma unroll
  for (int cs=0;cs<2;cs++){
    float mx = -1e30f;
    #pragma unroll
    for (int t=0;t<8;t++)
      mx = fmaxf(mx, fmaxf(fmaxf(acc1[cs][t][0], acc1[cs][t][1]),
                           fmaxf(acc1[cs][t][2], acc1[cs][t][3])));
    mx = fmaxf(mx, __shfl_xor(mx, 16));
    mx = fmaxf(mx, __shfl_xor(mx, 32));
    float sum = 0.f;
    #pragma unroll
    for (int t=0;t<8;t++){
      #pragma unroll
      for (int r4=0;r4<4;r4++){ float e = __expf(acc1[cs][t][r4] - mx); acc1[cs][t][r4] = e; sum += e; }
    }
    sum += __shfl_xor(sum, 16);
    sum += __shfl_xor(sum, 32);
    float inv = 1.f/sum;
    #pragma unroll
    for (int t=0;t<8;t++){
      a1p[cs][t][0] = pk2(acc1[cs][t][0]*inv, acc1[cs][t][1]*inv);
      a1p[cs][t][1] = pk2(acc1[cs][t][2]*inv, acc1[cs][t][3]*inv);
    }
  }

  // ---- V prefetch (used 2 phases later) ----
  uint4 vr[8];
  #pragma unroll
  for (int i=0;i<8;i++){
    size_t e = (size_t)(tid + 256*i)*8;
    vr[i] = *(const uint4*)(Vb + gbase + e);
  }

  __syncthreads();                   // all P1 LDS reads complete

  // ---- in-place transposed restage QT->X, KT->Y (from held regs) ----
  #pragma unroll
  for (int i=0;i<8;i++){
    int e = (tid + 256*i)*8;
    int row = e>>7, col = e&127;
    #pragma unroll
    for (int u=0;u<8;u++){
      int tr = col + u;
      *(unsigned short*)(X + tr*256 + swz(tr, row*2)) = elem16(qr[i], u);
      *(unsigned short*)(Y + tr*256 + swz(tr, row*2)) = elem16(kr[i], u);
    }
  }
  __syncthreads();

  // ---- P2: S2 = K^T·Q. D[m=i'][n=j']: i=ws+16cs+4lq+r4, j=jt*16+lm ----
  f32x4 acc2[2][8];
  #pragma unroll
  for (int cs=0;cs<2;cs++)
    #pragma unroll
    for (int t=0;t<8;t++) acc2[cs][t] = (f32x4){0.f,0.f,0.f,0.f};
  {
    bf16x8 akt[2][4];
    #pragma unroll
    for (int cs=0;cs<2;cs++)
      #pragma unroll
      for (int kk=0;kk<4;kk++){
        int ir = ws + 16*cs + lm;
        akt[cs][kk] = *(const bf16x8*)(Y + ir*256 + swz(ir, kk*64 + lq*16));
      }
    #pragma unroll
    for (int kk=0;kk<4;kk++){
      #pragma unroll
      for (int jt=0;jt<8;jt++){
        int jr = jt*16 + lm;
        bf16x8 bqt = *(const bf16x8*)(X + jr*256 + swz(jr, kk*64 + lq*16));
        acc2[0][jt] = __builtin_amdgcn_mfma_f32_16x16x32_bf16(akt[0][kk], bqt, acc2[0][jt], 0,0,0);
        acc2[1][jt] = __builtin_amdgcn_mfma_f32_16x16x32_bf16(akt[1][kk], bqt, acc2[1][jt], 0,0,0);
      }
    }
  }
  // softmax over j (per-reg in-lane over 8 tiles + shfl_xor 1..8), per cs
  unsigned int a2p[2][8][2];
  #pragma unroll
  for (int cs=0;cs<2;cs++){
    float m0=-1e30f, m1=-1e30f, m2=-1e30f, m3=-1e30f;
    #pragma unroll
    for (int t=0;t<8;t++){
      m0 = fmaxf(m0, acc2[cs][t][0]); m1 = fmaxf(m1, acc2[cs][t][1]);
      m2 = fmaxf(m2, acc2[cs][t][2]); m3 = fmaxf(m3, acc2[cs][t][3]);
    }
    #pragma unroll
    for (int d=1; d<16; d<<=1){
      m0 = fmaxf(m0, __shfl_xor(m0,d)); m1 = fmaxf(m1, __shfl_xor(m1,d));
      m2 = fmaxf(m2, __shfl_xor(m2,d)); m3 = fmaxf(m3, __shfl_xor(m3,d));
    }
    float s0=0.f, s1=0.f, s2=0.f, s3=0.f;
    #pragma unroll
    for (int t=0;t<8;t++){
      float e0 = __expf(acc2[cs][t][0]-m0); acc2[cs][t][0]=e0; s0 += e0;
      float e1 = __expf(acc2[cs][t][1]-m1); acc2[cs][t][1]=e1; s1 += e1;
      float e2 = __expf(acc2[cs][t][2]-m2); acc2[cs][t][2]=e2; s2 += e2;
      float e3 = __expf(acc2[cs][t][3]-m3); acc2[cs][t][3]=e3; s3 += e3;
    }
    #pragma unroll
    for (int d=1; d<16; d<<=1){
      s0 += __shfl_xor(s0,d); s1 += __shfl_xor(s1,d);
      s2 += __shfl_xor(s2,d); s3 += __shfl_xor(s3,d);
    }
    float i0=1.f/s0, i1=1.f/s1, i2=1.f/s2, i3=1.f/s3;
    #pragma unroll
    for (int t=0;t<8;t++){
      a2p[cs][t][0] = pk2(acc2[cs][t][0]*i0, acc2[cs][t][1]*i1);
      a2p[cs][t][1] = pk2(acc2[cs][t][2]*i2, acc2[cs][t][3]*i3);
    }
  }

  __syncthreads();                   // all P2 LDS reads complete

  // ---- stage VT -> X (from vr regs), A1 rm -> Y (from a1p) ----
  #pragma unroll
  for (int i=0;i<8;i++){
    int e = (tid + 256*i)*8;
    int row = e>>7, col = e&127;
    #pragma unroll
    for (int u=0;u<8;u++){
      int tr = col + u;
      *(unsigned short*)(X + tr*256 + swz(tr, row*2)) = elem16(vr[i], u);
    }
  }
  #pragma unroll
  for (int cs=0;cs<2;cs++){
    int r = ws + 16*cs + lm;
    #pragma unroll
    for (int t=0;t<8;t++)
      *(uint2*)(Y + r*256 + swz(r, t*32 + lq*8)) = make_uint2(a1p[cs][t][0], a1p[cs][t][1]);
  }
  __syncthreads();

  // ---- P3: MT = VT·A1^T. D[m=j'][n=r']: j=ws+16cs+4lq+r4, r=rt*16+lm ----
  f32x4 acc3[2][8];
  #pragma unroll
  for (int cs=0;cs<2;cs++)
    #pragma unroll
    for (int t=0;t<8;t++) acc3[cs][t] = (f32x4){0.f,0.f,0.f,0.f};
  {
    bf16x8 av[2][4];
    #pragma unroll
    for (int cs=0;cs<2;cs++)
      #pragma unroll
      for (int kk=0;kk<4;kk++){
        int jr = ws + 16*cs + lm;
        av[cs][kk] = *(const bf16x8*)(X + jr*256 + swz(jr, kk*64 + lq*16));
      }
    #pragma unroll
    for (int kk=0;kk<4;kk++){
      #pragma unroll
      for (int rt=0;rt<8;rt++){
        int rr = rt*16 + lm;
        bf16x8 ba = *(const bf16x8*)(Y + rr*256 + swz(rr, kk*64 + lq*16));
        acc3[0][rt] = __builtin_amdgcn_mfma_f32_16x16x32_bf16(av[0][kk], ba, acc3[0][rt], 0,0,0);
        acc3[1][rt] = __builtin_amdgcn_mfma_f32_16x16x32_bf16(av[1][kk], ba, acc3[1][rt], 0,0,0);
      }
    }
  }
  __syncthreads();                   // all P3 LDS reads complete

  // ---- store M rm -> X (transposed store), A2T rm -> Y ----
  #pragma unroll
  for (int cs=0;cs<2;cs++){
    #pragma unroll
    for (int rt=0;rt<8;rt++){
      int rr = rt*16 + lm;
      *(uint2*)(X + rr*256 + swz(rr, ws*2 + cs*32 + lq*8)) =
          make_uint2(pk2(acc3[cs][rt][0], acc3[cs][rt][1]),
                     pk2(acc3[cs][rt][2], acc3[cs][rt][3]));
    }
  }
  #pragma unroll
  for (int cs=0;cs<2;cs++){
    #pragma unroll
    for (int t=0;t<8;t++){
      int jr = t*16 + lm;
      *(uint2*)(Y + jr*256 + swz(jr, ws*2 + cs*32 + lq*8)) =
          make_uint2(a2p[cs][t][0], a2p[cs][t][1]);
    }
  }
  __syncthreads();

  // ---- P4: P = M·A2. D[m][n]: r=ws+16cs+4lq+r4, j=jt*16+lm -> global ----
  f32x4 acc4[2][8];
  #pragma unroll
  for (int cs=0;cs<2;cs++)
    #pragma unroll
    for (int t=0;t<8;t++) acc4[cs][t] = (f32x4){0.f,0.f,0.f,0.f};
  {
    bf16x8 am[2][4];
    #pragma unroll
    for (int cs=0;cs<2;cs++)
      #pragma unroll
      for (int kk=0;kk<4;kk++){
        int rr = ws + 16*cs + lm;
        am[cs][kk] = *(const bf16x8*)(X + rr*256 + swz(rr, kk*64 + lq*16));
      }
    #pragma unroll
    for (int kk=0;kk<4;kk++){
      #pragma unroll
      for (int jt=0;jt<8;jt++){
        int jr = jt*16 + lm;
        bf16x8 ba2 = *(const bf16x8*)(Y + jr*256 + swz(jr, kk*64 + lq*16));
        acc4[0][jt] = __builtin_amdgcn_mfma_f32_16x16x32_bf16(am[0][kk], ba2, acc4[0][jt], 0,0,0);
        acc4[1][jt] = __builtin_amdgcn_mfma_f32_16x16x32_bf16(am[1][kk], ba2, acc4[1][jt], 0,0,0);
      }
    }
  }
  unsigned short* pout = Pb + gbase;
  #pragma unroll
  for (int cs=0;cs<2;cs++){
    #pragma unroll
    for (int jt=0;jt<8;jt++){
      #pragma unroll
      for (int r4=0;r4<4;r4++){
        int rr = ws + 16*cs + 4*lq + r4;
        pout[rr*HH + jt*16 + lm] = f2bf(acc4[cs][jt][r4]);
      }
    }
  }
}

// ---------------- Kernel 3: out = relu(conv1x1(P, w3, b3)) fp32, MFMA -----
// LDS = Xs only (16KB): W3 frags direct from global -> 6-8 blocks/CU.
__global__ __launch_bounds__(256, 6) void rc_conv_out(
    const unsigned short* __restrict__ Pb, const float* __restrict__ w3,
    const float* __restrict__ b3, float* __restrict__ out)
{
  __shared__ char Xs[16384];           // 128 p-rows x 128 B

  const int tid = threadIdx.x;
  const int b  = blockIdx.y;
  const int pblock = blockIdx.x * 128;
  const int w = tid>>6, l = tid&63, lq = l>>4, lm = l&15;
  const int orow = 16*w + lm;

  bf16x8 aW[2];
  {
    const float* wp = w3 + orow*64;
    float4 a0 = *(const float4*)(wp + lq*8);
    float4 a1 = *(const float4*)(wp + lq*8 + 4);
    float4 a2 = *(const float4*)(wp + 32 + lq*8);
    float4 a3 = *(const float4*)(wp + 32 + lq*8 + 4);
    aW[0] = pk8(a0, a1); aW[1] = pk8(a2, a3);
  }
  float4 bv4 = *(const float4*)(b3 + 16*w + 4*lq);
  const float* bv = (const float*)&bv4;

  // ---- stage P tile: all 8 loads in flight, then pack to LDS ----
  const unsigned short* S = Pb + (size_t)b*NCH*NPOS + pblock;
  uint2 pr[2][4];
  #pragma unroll
  for (int g=0; g<2; ++g){
    int unit = tid + 256*g;
    int q  = unit >> 5;
    int p4 = (unit & 31) << 2;
    #pragma unroll
    for (int j=0;j<4;j++)
      pr[g][j] = *(const uint2*)(S + (size_t)(4*q+j)*NPOS + p4);
  }
  #pragma unroll
  for (int g=0; g<2; ++g){
    int unit = tid + 256*g;
    int q  = unit >> 5;
    int p4 = (unit & 31) << 2;
    const unsigned short* e0 = (const unsigned short*)&pr[g][0];
    const unsigned short* e1 = (const unsigned short*)&pr[g][1];
    const unsigned short* e2 = (const unsigned short*)&pr[g][2];
    const unsigned short* e3 = (const unsigned short*)&pr[g][3];
    #pragma unroll
    for (int u=0; u<4; ++u){
      uint2 pk;
      pk.x = (unsigned int)e0[u] | ((unsigned int)e1[u]<<16);
      pk.y = (unsigned int)e2[u] | ((unsigned int)e3[u]<<16);
      *(uint2*)(Xs + (p4+u)*128 + swz(p4+u, q*8)) = pk;
    }
  }
  __syncthreads();

  float* dst = out + (size_t)b*NCH*NPOS;
  #pragma unroll
  for (int pt=0; pt<8; ++pt){
    int prow = pt*16 + lm;
    bf16x8 bx0 = *(const bf16x8*)(Xs + prow*128 + swz(prow,      lq*16));
    bf16x8 bx1 = *(const bf16x8*)(Xs + prow*128 + swz(prow, 64 + lq*16));
    f32x4 acc = (f32x4){0.f,0.f,0.f,0.f};
    acc = __builtin_amdgcn_mfma_f32_16x16x32_bf16(aW[0], bx0, acc, 0,0,0);
    acc = __builtin_amdgcn_mfma_f32_16x16x32_bf16(aW[1], bx1, acc, 0,0,0);
    int p = pblock + pt*16 + lm;
    #pragma unroll
    for (int r4=0;r4<4;r4++){
      int o = 16*w + 4*lq + r4;
      dst[(size_t)o*NPOS + p] = fmaxf(acc[r4] + bv[r4], 0.f);
    }
  }
}

extern "C" void kernel_launch(void* const* d_in, const int* in_sizes, int n_in,
                              void* d_out, int out_size, void* d_ws, size_t ws_size,
                              hipStream_t stream)
{
  const float* x   = (const float*)d_in[0];
  const float* att = (const float*)d_in[1];
  const float* w0  = (const float*)d_in[2]; const float* b0 = (const float*)d_in[3];
  const float* w1  = (const float*)d_in[4]; const float* b1 = (const float*)d_in[5];
  const float* w2  = (const float*)d_in[6]; const float* b2 = (const float*)d_in[7];
  const float* w3  = (const float*)d_in[8]; const float* b3 = (const float*)d_in[9];

  const size_t NM = (size_t)NB*NCH*NPOS;          // 16,777,216 elems per matrix
  unsigned short* Qb = (unsigned short*)d_ws;     // bf16, 33.55 MB each
  unsigned short* Kb = Qb + NM;
  unsigned short* Vb = Kb + NM;
  unsigned short* Pb = Vb + NM;
  float* out = (float*)d_out;

  (void)hipFuncSetAttribute((const void*)rc_attention_mfma,
                            hipFuncAttributeMaxDynamicSharedMemorySize, 65536);

  rc_conv_in<<<dim3(128, NB, 2), 256, 0, stream>>>(x, att, w0,b0, w1,b1, w2,b2,
                                                   Qb, Kb, Vb);

  rc_attention_mfma<<<dim3(NB*NCH), 256, 65536, stream>>>(Qb, Kb, Vb, Pb);

  rc_conv_out<<<dim3(128, NB), 256, 0, stream>>>(Pb, w3, b3, out);
}